// Round 2
// baseline (1095.003 us; speedup 1.0000x reference)
//
#include <hip/hip_runtime.h>
#include <hip/hip_bf16.h>

#define BM 128
#define BN 128
#define BK 32

typedef __attribute__((ext_vector_type(8))) short bf16x8;
typedef __attribute__((ext_vector_type(4))) float f32x4;

__device__ __forceinline__ unsigned short f2bf_rne(float f) {
  unsigned int u = __float_as_uint(f);
  u += 0x7FFFu + ((u >> 16) & 1u);
  return (unsigned short)(u >> 16);
}

__device__ __forceinline__ float bf2f(unsigned short h) {
  return __uint_as_float(((unsigned int)h) << 16);
}

// ---------- pass 1: sum(|w|) in fp64 ----------
__global__ void absmean_kernel(const float* __restrict__ w, long n, double* __restrict__ out) {
  double s = 0.0;
  long stride = (long)gridDim.x * blockDim.x * 4;
  for (long i = ((long)blockIdx.x * blockDim.x + threadIdx.x) * 4; i < n; i += stride) {
    float4 v = *(const float4*)(w + i);
    s += (double)fabsf(v.x) + (double)fabsf(v.y) + (double)fabsf(v.z) + (double)fabsf(v.w);
  }
  for (int o = 32; o > 0; o >>= 1) s += __shfl_down(s, o, 64);
  __shared__ double ls[4];
  int lane = threadIdx.x & 63, wv = threadIdx.x >> 6;
  if (lane == 0) ls[wv] = s;
  __syncthreads();
  if (threadIdx.x == 0) atomicAdd(out, ls[0] + ls[1] + ls[2] + ls[3]);
}

// ---------- pass 2a: x -> [hi | lo] bf16, row-major [M][2K] ----------
__global__ void prep_x_kernel(const float* __restrict__ x, unsigned short* __restrict__ xcat,
                              int K, int Kc, long n) {
  long stride = (long)gridDim.x * blockDim.x * 4;
  for (long i = ((long)blockIdx.x * blockDim.x + threadIdx.x) * 4; i < n; i += stride) {
    float4 v = *(const float4*)(x + i);
    float f[4] = {v.x, v.y, v.z, v.w};
    unsigned short hi[4], lo[4];
#pragma unroll
    for (int j = 0; j < 4; ++j) {
      hi[j] = f2bf_rne(f[j]);
      lo[j] = f2bf_rne(f[j] - bf2f(hi[j]));
    }
    long row = i / K;
    int col = (int)(i - row * K);
    unsigned short* p0 = xcat + row * (long)Kc + col;
    *(ushort4*)p0 = make_ushort4(hi[0], hi[1], hi[2], hi[3]);
    *(ushort4*)(p0 + K) = make_ushort4(lo[0], lo[1], lo[2], lo[3]);
  }
}

// ---------- pass 2b: w -> ternary bf16, duplicated [N][2K] ----------
__global__ void prep_w_kernel(const float* __restrict__ w, unsigned short* __restrict__ wcat,
                              const double* __restrict__ sum, int K, int Kc, long n,
                              double inv_cnt) {
  float scale = 1e-5f + (float)(*sum * inv_cnt);
  long stride = (long)gridDim.x * blockDim.x * 4;
  for (long i = ((long)blockIdx.x * blockDim.x + threadIdx.x) * 4; i < n; i += stride) {
    float4 v = *(const float4*)(w + i);
    float f[4] = {v.x, v.y, v.z, v.w};
    unsigned short q[4];
#pragma unroll
    for (int j = 0; j < 4; ++j) {
      float t = f[j] / scale;       // fp32 divide, as in reference
      t = rintf(t);                 // round-half-even, matches jnp.round
      t = fminf(1.0f, fmaxf(-1.0f, t));
      q[j] = f2bf_rne(t);           // exact for {-1,0,1}
    }
    long row = i / K;
    int col = (int)(i - row * K);
    unsigned short* p0 = wcat + row * (long)Kc + col;
    *(ushort4*)p0 = make_ushort4(q[0], q[1], q[2], q[3]);
    *(ushort4*)(p0 + K) = make_ushort4(q[0], q[1], q[2], q[3]);
  }
}

// ---------- async global->LDS, 16B per lane ----------
__device__ __forceinline__ void gll16(const unsigned short* g, void* l) {
  __builtin_amdgcn_global_load_lds((const __attribute__((address_space(1))) unsigned int*)g,
                                   (__attribute__((address_space(3))) unsigned int*)l,
                                   16, 0, 0);
}

// ---------- main GEMM: C[M][N] = A[M][Kc] * B[N][Kc]^T + bias ----------
// 1D grid, XCD-aware swizzle (nwg = 64*64 = 4096, divisible by 8 -> bijective)
__global__ __launch_bounds__(256) void gemm_kernel(
    const unsigned short* __restrict__ A,
    const unsigned short* __restrict__ Bw,
    const float* __restrict__ bias,
    float* __restrict__ C, int M, int N, int Kc) {
  __shared__ __align__(16) unsigned short As[BM * BK];  // 8 KB
  __shared__ __align__(16) unsigned short Bs[BN * BK];  // 8 KB

  const int nbx = N / BN;
  const int nwg = (M / BM) * nbx;
  const int cpx = nwg >> 3;                    // chunk per XCD
  const int orig = blockIdx.x;
  const int wgid = (orig & 7) * cpx + (orig >> 3);  // XCD swizzle (T1)
  const int bx = wgid % nbx;
  const int by = wgid / nbx;

  const int tid = threadIdx.x;
  const int lane = tid & 63;
  const int wv = tid >> 6;
  const int bm = by * BM;
  const int bn = bx * BN;
  const int wm = (wv >> 1) * 64;  // wave's 64x64 quadrant
  const int wn = (wv & 1) * 64;

  f32x4 acc[4][4] = {};

  // staging: 256 threads x 16B = 4KB/issue; lane l of wave wv lands at
  // LDS byte wv*1024 + l*16 == row-major [128][32] linear (desk-checked)
  const int srow = tid >> 2;
  const int scol = (tid & 3) * 8;
  const unsigned short* a0 = A + (size_t)(bm + srow) * Kc + scol;
  const unsigned short* a1 = A + (size_t)(bm + 64 + srow) * Kc + scol;
  const unsigned short* b0 = Bw + (size_t)(bn + srow) * Kc + scol;
  const unsigned short* b1 = Bw + (size_t)(bn + 64 + srow) * Kc + scol;
  char* asb = (char*)As + (size_t)wv * 1024;  // wave-uniform LDS dest base
  char* bsb = (char*)Bs + (size_t)wv * 1024;

  // fragment read offsets (elements): row-major [128][32]
  const int ar = (wm + (lane & 15)) * BK + (lane >> 4) * 8;
  const int br = (wn + (lane & 15)) * BK + (lane >> 4) * 8;

  for (int k0 = 0; k0 < Kc; k0 += BK) {
    gll16(a0 + k0, asb);
    gll16(a1 + k0, asb + 4096);
    gll16(b0 + k0, bsb);
    gll16(b1 + k0, bsb + 4096);
    __syncthreads();
    bf16x8 af[4], bfr[4];
#pragma unroll
    for (int t = 0; t < 4; ++t) {
      af[t] = *(const bf16x8*)(As + ar + t * 16 * BK);
      bfr[t] = *(const bf16x8*)(Bs + br + t * 16 * BK);
    }
#pragma unroll
    for (int i = 0; i < 4; ++i)
#pragma unroll
      for (int j = 0; j < 4; ++j)
        acc[i][j] = __builtin_amdgcn_mfma_f32_16x16x32_bf16(af[i], bfr[j], acc[i][j], 0, 0, 0);
    __syncthreads();
  }

  // epilogue: C/D layout col=lane&15, row=(lane>>4)*4+reg (m89-verified)
  const int r0 = bm + wm + (lane >> 4) * 4;
  const int c0 = bn + wn + (lane & 15);
#pragma unroll
  for (int j = 0; j < 4; ++j) {
    const int col = c0 + j * 16;
    const float bv = bias[col];
#pragma unroll
    for (int i = 0; i < 4; ++i) {
#pragma unroll
      for (int r = 0; r < 4; ++r)
        C[(size_t)(r0 + i * 16 + r) * N + col] = acc[i][j][r] + bv;
    }
  }
}

// ---------- fallback (ws too small): fp32 tiled, quantize on the fly ----------
__global__ void fallback_kernel(const float* __restrict__ x, const float* __restrict__ w,
                                const float* __restrict__ bias, const double* __restrict__ sum,
                                float* __restrict__ out, int M, int N, int K, double inv_cnt) {
  float scale = 1e-5f + (float)(*sum * inv_cnt);
  __shared__ float xs[64][33];
  __shared__ float qs[64][33];
  const int tid = threadIdx.x;
  const int bm = blockIdx.y * 64, bn = blockIdx.x * 64;
  const int ty = tid >> 4, tx = tid & 15;
  float acc[4][4] = {};
  for (int k0 = 0; k0 < K; k0 += 32) {
    for (int p = 0; p < 8; ++p) {
      int idx = p * 256 + tid;
      int r = idx >> 5, c = idx & 31;
      xs[r][c] = x[(size_t)(bm + r) * K + k0 + c];
      float t = w[(size_t)(bn + r) * K + k0 + c] / scale;
      t = rintf(t);
      qs[r][c] = fminf(1.0f, fmaxf(-1.0f, t));
    }
    __syncthreads();
    for (int kk = 0; kk < 32; ++kk) {
      float a[4], b[4];
#pragma unroll
      for (int i = 0; i < 4; ++i) a[i] = xs[ty * 4 + i][kk];
#pragma unroll
      for (int j = 0; j < 4; ++j) b[j] = qs[tx * 4 + j][kk];
#pragma unroll
      for (int i = 0; i < 4; ++i)
#pragma unroll
        for (int j = 0; j < 4; ++j) acc[i][j] += a[i] * b[j];
    }
    __syncthreads();
  }
#pragma unroll
  for (int i = 0; i < 4; ++i)
#pragma unroll
    for (int j = 0; j < 4; ++j)
      out[(size_t)(bm + ty * 4 + i) * N + bn + tx * 4 + j] = acc[i][j] + bias[bn + tx * 4 + j];
}

extern "C" void kernel_launch(void* const* d_in, const int* in_sizes, int n_in,
                              void* d_out, int out_size, void* d_ws, size_t ws_size,
                              hipStream_t stream) {
  const float* x = (const float*)d_in[0];
  const float* w = (const float*)d_in[1];
  const float* bias = (const float*)d_in[2];
  float* out = (float*)d_out;

  const int K = 2048;
  const int M = in_sizes[0] / K;  // 8192 (= B*S)
  const int N = in_sizes[2];      // 8192
  const int Kc = 2 * K;           // 4096 (hi|lo)
  const long nw = (long)N * K;
  const long nx = (long)M * K;
  const double inv_cnt = 1.0 / (double)nw;

  double* sum = (double*)d_ws;
  hipMemsetAsync(d_ws, 0, sizeof(double), stream);
  absmean_kernel<<<2048, 256, 0, stream>>>(w, nw, sum);

  size_t need = 256 + ((size_t)M + (size_t)N) * (size_t)Kc * sizeof(unsigned short);
  if (ws_size >= need) {
    unsigned short* xcat = (unsigned short*)((char*)d_ws + 256);
    unsigned short* wcat = xcat + (size_t)M * Kc;
    prep_x_kernel<<<2048, 256, 0, stream>>>(x, xcat, K, Kc, nx);
    prep_w_kernel<<<2048, 256, 0, stream>>>(w, wcat, sum, K, Kc, nw, inv_cnt);
    int nwg = (M / BM) * (N / BN);
    gemm_kernel<<<nwg, 256, 0, stream>>>(xcat, wcat, bias, out, M, N, Kc);
  } else {
    dim3 grid(N / 64, M / 64);
    fallback_kernel<<<grid, 256, 0, stream>>>(x, w, bias, sum, out, M, N, K, inv_cnt);
  }
}

// Round 7
// 927.016 us; speedup vs baseline: 1.1812x; 1.1812x over previous
//
#include <hip/hip_runtime.h>
#include <hip/hip_bf16.h>

typedef __attribute__((ext_vector_type(8))) short bf16x8;
typedef __attribute__((ext_vector_type(4))) float f32x4;

__device__ __forceinline__ unsigned short f2bf_rne(float f) {
  unsigned int u = __float_as_uint(f);
  u += 0x7FFFu + ((u >> 16) & 1u);
  return (unsigned short)(u >> 16);
}

__device__ __forceinline__ float bf2f(unsigned short h) {
  return __uint_as_float(((unsigned int)h) << 16);
}

// ---------- pass 1: sum(|w|) in fp64 (numerics locked - passed R2) ----------
__global__ void absmean_kernel(const float* __restrict__ w, long n, double* __restrict__ out) {
  double s = 0.0;
  long stride = (long)gridDim.x * blockDim.x * 4;
  for (long i = ((long)blockIdx.x * blockDim.x + threadIdx.x) * 4; i < n; i += stride) {
    float4 v = *(const float4*)(w + i);
    s += (double)fabsf(v.x) + (double)fabsf(v.y) + (double)fabsf(v.z) + (double)fabsf(v.w);
  }
  for (int o = 32; o > 0; o >>= 1) s += __shfl_down(s, o, 64);
  __shared__ double ls[4];
  int lane = threadIdx.x & 63, wv = threadIdx.x >> 6;
  if (lane == 0) ls[wv] = s;
  __syncthreads();
  if (threadIdx.x == 0) atomicAdd(out, ls[0] + ls[1] + ls[2] + ls[3]);
}

// ---------- pass 2a: x -> [hi | lo] bf16, row-major [M][2K] ----------
// kshift = log2(K); pow2 shapes only on this path (checked host-side)
__global__ void prep_x_kernel(const float* __restrict__ x, unsigned short* __restrict__ xcat,
                              int kshift, long n) {
  const int K = 1 << kshift;
  long stride = (long)gridDim.x * blockDim.x * 4;
  for (long i = ((long)blockIdx.x * blockDim.x + threadIdx.x) * 4; i < n; i += stride) {
    float4 v = *(const float4*)(x + i);
    float f[4] = {v.x, v.y, v.z, v.w};
    unsigned short hi[4], lo[4];
#pragma unroll
    for (int j = 0; j < 4; ++j) {
      hi[j] = f2bf_rne(f[j]);
      lo[j] = f2bf_rne(f[j] - bf2f(hi[j]));
    }
    long row = i >> kshift;
    int col = (int)(i & (K - 1));
    unsigned short* p0 = xcat + (row << (kshift + 1)) + col;
    *(ushort4*)p0 = make_ushort4(hi[0], hi[1], hi[2], hi[3]);
    *(ushort4*)(p0 + K) = make_ushort4(lo[0], lo[1], lo[2], lo[3]);
  }
}

// ---------- pass 2b: w -> ternary bf16, duplicated [N][2K] ----------
__global__ void prep_w_kernel(const float* __restrict__ w, unsigned short* __restrict__ wcat,
                              const double* __restrict__ sum, int kshift, long n,
                              double inv_cnt) {
  const int K = 1 << kshift;
  float scale = 1e-5f + (float)(*sum * inv_cnt);
  long stride = (long)gridDim.x * blockDim.x * 4;
  for (long i = ((long)blockIdx.x * blockDim.x + threadIdx.x) * 4; i < n; i += stride) {
    float4 v = *(const float4*)(w + i);
    float f[4] = {v.x, v.y, v.z, v.w};
    unsigned short q[4];
#pragma unroll
    for (int j = 0; j < 4; ++j) {
      float t = f[j] / scale;
      t = rintf(t);
      t = fminf(1.0f, fmaxf(-1.0f, t));
      q[j] = f2bf_rne(t);
    }
    long row = i >> kshift;
    int col = (int)(i & (K - 1));
    unsigned short* p0 = wcat + (row << (kshift + 1)) + col;
    *(ushort4*)p0 = make_ushort4(q[0], q[1], q[2], q[3]);
    *(ushort4*)(p0 + K) = make_ushort4(q[0], q[1], q[2], q[3]);
  }
}

// ---------- async global->LDS, 16B per lane ----------
__device__ __forceinline__ void gll16(const unsigned short* g, void* l) {
  __builtin_amdgcn_global_load_lds((const __attribute__((address_space(1))) unsigned int*)g,
                                   (__attribute__((address_space(3))) unsigned int*)l,
                                   16, 0, 0);
}

// =====================================================================
// 256x256 tile, BK=32, 4-deep LDS ring, 8 waves, 2 phases per K-tile.
// T1 (m204 bijective XCD swizzle) + T3/T4 (phase split, counted vmcnt(8))
// + T5 (setprio). LDS: A ring 4x[256][32]bf16 @ byte 0; B ring @ 65536.
// Ring invariant (4x desk-checked, incl. explicit vmcnt induction):
//   iter t top: outstanding=8 (tiles t+1,t+2); issues tile t+3 (->12);
//   end vmcnt(8) retires tile t+1; barrier publishes it. WAR on buffer
//   (t-1)&3 closed by per-wave lgkmcnt(0) before final-barrier arrival.
// Drain: vmcnt(4) @ t=NT-3, vmcnt(0) @ t=NT-2.
// Swizzle bijection: physical slot p at row r holds global chunk p^(r&3);
// read of chunk c=lane>>4 at row r=lane&15 uses p=(lane>>4)^(lane&3). OK.
// Bank audit: group g=slot+4*(row&1); wave hits 8 groups x 8 = b128 floor.
// =====================================================================
__global__ __launch_bounds__(512) void gemm8p_kernel(
    const unsigned short* __restrict__ A,
    const unsigned short* __restrict__ Bw,
    const float* __restrict__ bias,
    float* __restrict__ C, int M, int N) {
  constexpr int Kc = 4096;
  constexpr int NT = 128;               // Kc / 32
  __shared__ __align__(16) unsigned short lds[65536];  // 128 KiB

  const int nbx = N >> 8;
  const int nwg = (M >> 8) * nbx;
  // m204 bijective XCD swizzle
  const int q8 = nwg >> 3, r8 = nwg & 7;
  const int xcd = blockIdx.x & 7;
  const int loc = blockIdx.x >> 3;
  const int wgid = (xcd < r8 ? xcd * (q8 + 1) : r8 * (q8 + 1) + (xcd - r8) * q8) + loc;
  const int bx = wgid % nbx;
  const int by = wgid / nbx;
  const int bm = by << 8;
  const int bn = bx << 8;

  const int tid = threadIdx.x;
  const int lane = tid & 63;
  const int wid = tid >> 6;
  const int wr = wid >> 2;              // 0..1 : wave row (128 rows each)
  const int wc = wid & 3;               // 0..3 : wave col (64 cols each)

  f32x4 acc[8][4] = {};

  // ---- staging addresses (pre-swizzled global source; linear LDS dest) ----
  const int strow = tid >> 2;                               // 0..127
  const int sslot = ((tid & 3) ^ ((tid >> 2) & 3)) * 8;     // elem offset
  const unsigned short* sA0 = A + (size_t)(bm + strow) * Kc + sslot;
  const unsigned short* sA1 = A + (size_t)(bm + 128 + strow) * Kc + sslot;
  const unsigned short* sB0 = Bw + (size_t)(bn + strow) * Kc + sslot;
  const unsigned short* sB1 = Bw + (size_t)(bn + 128 + strow) * Kc + sslot;
  char* dA = (char*)lds + (size_t)wid * 1024;               // + buf*16384 (+8192 half2)
  char* dB = (char*)lds + 65536 + (size_t)wid * 1024;

  // ---- fragment read offsets (elements), matching swizzle ----
  const int scol = (((lane >> 4) ^ (lane & 3)) << 3);
  const int aoff = (wr * 128 + (lane & 15)) * 32 + scol;            // A region
  const int boff = 32768 + (wc * 64 + (lane & 15)) * 32 + scol;     // B region

  // ---- prologue: stage tiles 0,1,2 ----
#pragma unroll
  for (int p = 0; p < 3; ++p) {
    gll16(sA0 + p * 32, dA + p * 16384);
    gll16(sA1 + p * 32, dA + p * 16384 + 8192);
    gll16(sB0 + p * 32, dB + p * 16384);
    gll16(sB1 + p * 32, dB + p * 16384 + 8192);
  }
  asm volatile("s_waitcnt vmcnt(8)" ::: "memory");   // tile 0 (this wave) done
  __builtin_amdgcn_s_barrier();                      // all waves -> tile 0 resident

  bf16x8 a_[4], b_[4];
  for (int t = 0; t < NT; ++t) {
    const unsigned short* base = lds + (t & 3) * 8192;
    const int sb = (t + 3) & 3;
    const int sk = (t + 3) * 32;
    const bool doStage = (t + 3) < NT;

    // ---------------- phase 1: m 0..3  x  n 0..3 ----------------
#pragma unroll
    for (int mi = 0; mi < 4; ++mi)
      a_[mi] = *(const bf16x8*)&base[aoff + mi * 512];
#pragma unroll
    for (int ni = 0; ni < 4; ++ni)
      b_[ni] = *(const bf16x8*)&base[boff + ni * 512];
    if (doStage) {
      gll16(sA0 + sk, dA + sb * 16384);
      gll16(sA1 + sk, dA + sb * 16384 + 8192);
    }
    __builtin_amdgcn_s_barrier();
    asm volatile("s_waitcnt lgkmcnt(0)" ::: "memory");
    __builtin_amdgcn_sched_barrier(0);               // rule #18: fence MFMA hoist
    __builtin_amdgcn_s_setprio(1);
#pragma unroll
    for (int mi = 0; mi < 4; ++mi)
#pragma unroll
      for (int ni = 0; ni < 4; ++ni)
        acc[mi][ni] = __builtin_amdgcn_mfma_f32_16x16x32_bf16(a_[mi], b_[ni], acc[mi][ni], 0, 0, 0);
    __builtin_amdgcn_s_setprio(0);
    __builtin_amdgcn_s_barrier();

    // ------------- phase 2: m 4..7 x n 0..3 (b_ reused) -------------
#pragma unroll
    for (int mi = 0; mi < 4; ++mi)
      a_[mi] = *(const bf16x8*)&base[aoff + (mi + 4) * 512];
    if (doStage) {
      gll16(sB0 + sk, dB + sb * 16384);
      gll16(sB1 + sk, dB + sb * 16384 + 8192);
    }
    __builtin_amdgcn_s_barrier();
    asm volatile("s_waitcnt lgkmcnt(0)" ::: "memory");
    __builtin_amdgcn_sched_barrier(0);
    __builtin_amdgcn_s_setprio(1);
#pragma unroll
    for (int mi = 0; mi < 4; ++mi)
#pragma unroll
      for (int ni = 0; ni < 4; ++ni)
        acc[mi + 4][ni] = __builtin_amdgcn_mfma_f32_16x16x32_bf16(a_[mi], b_[ni], acc[mi + 4][ni], 0, 0, 0);
    __builtin_amdgcn_s_setprio(0);
    // counted vmcnt once per K-tile (T4): never 0 in steady state
    if (t < NT - 3) {
      asm volatile("s_waitcnt vmcnt(8)" ::: "memory");
    } else if (t == NT - 3) {
      asm volatile("s_waitcnt vmcnt(4)" ::: "memory");
    } else if (t == NT - 2) {
      asm volatile("s_waitcnt vmcnt(0)" ::: "memory");
    }
    __builtin_amdgcn_s_barrier();
  }

  // ---- epilogue: C/D layout col=lane&15, row=(lane>>4)*4+reg ----
  const int r0 = bm + wr * 128 + (lane >> 4) * 4;
  const int c0 = bn + wc * 64 + (lane & 15);
#pragma unroll
  for (int ni = 0; ni < 4; ++ni) {
    const int col = c0 + ni * 16;
    const float bv = bias[col];
#pragma unroll
    for (int mi = 0; mi < 8; ++mi) {
#pragma unroll
      for (int rr = 0; rr < 4; ++rr)
        C[(size_t)(r0 + mi * 16 + rr) * N + col] = acc[mi][ni][rr] + bv;
    }
  }
}

// ---------- fallback (generic shapes / tiny ws): fp32 tiled ----------
__global__ void fallback_kernel(const float* __restrict__ x, const float* __restrict__ w,
                                const float* __restrict__ bias, const double* __restrict__ sum,
                                float* __restrict__ out, int M, int N, int K, double inv_cnt) {
  float scale = 1e-5f + (float)(*sum * inv_cnt);
  __shared__ float xs[64][33];
  __shared__ float qs[64][33];
  const int tid = threadIdx.x;
  const int bm = blockIdx.y * 64, bn = blockIdx.x * 64;
  const int ty = tid >> 4, tx = tid & 15;
  float acc[4][4] = {};
  for (int k0 = 0; k0 < K; k0 += 32) {
    for (int p = 0; p < 8; ++p) {
      int idx = p * 256 + tid;
      int r = idx >> 5, c = idx & 31;
      xs[r][c] = x[(size_t)(bm + r) * K + k0 + c];
      float t = w[(size_t)(bn + r) * K + k0 + c] / scale;
      t = rintf(t);
      qs[r][c] = fminf(1.0f, fmaxf(-1.0f, t));
    }
    __syncthreads();
    for (int kk = 0; kk < 32; ++kk) {
      float a[4], b[4];
#pragma unroll
      for (int i = 0; i < 4; ++i) a[i] = xs[ty * 4 + i][kk];
#pragma unroll
      for (int j = 0; j < 4; ++j) b[j] = qs[tx * 4 + j][kk];
#pragma unroll
      for (int i = 0; i < 4; ++i)
#pragma unroll
        for (int j = 0; j < 4; ++j) acc[i][j] += a[i] * b[j];
    }
    __syncthreads();
  }
#pragma unroll
  for (int i = 0; i < 4; ++i)
#pragma unroll
    for (int j = 0; j < 4; ++j)
      out[(size_t)(bm + ty * 4 + i) * N + bn + tx * 4 + j] = acc[i][j] + bias[bn + tx * 4 + j];
}

extern "C" void kernel_launch(void* const* d_in, const int* in_sizes, int n_in,
                              void* d_out, int out_size, void* d_ws, size_t ws_size,
                              hipStream_t stream) {
  const float* x = (const float*)d_in[0];
  const float* w = (const float*)d_in[1];
  const float* bias = (const float*)d_in[2];
  float* out = (float*)d_out;

  const int K = 2048;
  const int kshift = 11;          // log2(K)
  const int M = in_sizes[0] / K;  // 8192
  const int N = in_sizes[2];      // 8192
  const int Kc = 2 * K;           // 4096 (hi|lo)
  const long nw = (long)N * K;
  const long nx = (long)M * K;
  const double inv_cnt = 1.0 / (double)nw;

  double* sum = (double*)d_ws;
  hipMemsetAsync(d_ws, 0, sizeof(double), stream);
  absmean_kernel<<<2048, 256, 0, stream>>>(w, nw, sum);

  size_t need = 256 + ((size_t)M + (size_t)N) * (size_t)Kc * sizeof(unsigned short);
  bool shapes_ok = (K == 2048) && ((M & 255) == 0) && ((N & 255) == 0);
  if (shapes_ok && ws_size >= need) {
    unsigned short* xcat = (unsigned short*)((char*)d_ws + 256);
    unsigned short* wcat = xcat + (size_t)M * Kc;
    prep_x_kernel<<<2048, 256, 0, stream>>>(x, xcat, kshift, nx);
    prep_w_kernel<<<2048, 256, 0, stream>>>(w, wcat, sum, kshift, nw, inv_cnt);
    int nwg = (M >> 8) * (N >> 8);
    gemm8p_kernel<<<nwg, 512, 0, stream>>>(xcat, wcat, bias, out, M, N);
  } else {
    dim3 grid(N / 64, M / 64);
    fallback_kernel<<<grid, 256, 0, stream>>>(x, w, bias, sum, out, M, N, K, inv_cnt);
  }
}

// Round 8
// 923.771 us; speedup vs baseline: 1.1854x; 1.0035x over previous
//
#include <hip/hip_runtime.h>
#include <hip/hip_bf16.h>

typedef __attribute__((ext_vector_type(8))) short bf16x8;
typedef __attribute__((ext_vector_type(4))) float f32x4;

__device__ __forceinline__ unsigned short f2bf_rne(float f) {
  unsigned int u = __float_as_uint(f);
  u += 0x7FFFu + ((u >> 16) & 1u);
  return (unsigned short)(u >> 16);
}

__device__ __forceinline__ float bf2f(unsigned short h) {
  return __uint_as_float(((unsigned int)h) << 16);
}

// ---------- pass 1: sum(|w|) in fp64 (numerics locked - passed R2/R7) ----------
__global__ void absmean_kernel(const float* __restrict__ w, long n, double* __restrict__ out) {
  double s = 0.0;
  long stride = (long)gridDim.x * blockDim.x * 4;
  for (long i = ((long)blockIdx.x * blockDim.x + threadIdx.x) * 4; i < n; i += stride) {
    float4 v = *(const float4*)(w + i);
    s += (double)fabsf(v.x) + (double)fabsf(v.y) + (double)fabsf(v.z) + (double)fabsf(v.w);
  }
  for (int o = 32; o > 0; o >>= 1) s += __shfl_down(s, o, 64);
  __shared__ double ls[4];
  int lane = threadIdx.x & 63, wv = threadIdx.x >> 6;
  if (lane == 0) ls[wv] = s;
  __syncthreads();
  if (threadIdx.x == 0) atomicAdd(out, ls[0] + ls[1] + ls[2] + ls[3]);
}

// ---------- pass 2a: x -> [hi | lo] bf16, row-major [M][2K] ----------
__global__ void prep_x_kernel(const float* __restrict__ x, unsigned short* __restrict__ xcat,
                              int kshift, long n) {
  const int K = 1 << kshift;
  long stride = (long)gridDim.x * blockDim.x * 4;
  for (long i = ((long)blockIdx.x * blockDim.x + threadIdx.x) * 4; i < n; i += stride) {
    float4 v = *(const float4*)(x + i);
    float f[4] = {v.x, v.y, v.z, v.w};
    unsigned short hi[4], lo[4];
#pragma unroll
    for (int j = 0; j < 4; ++j) {
      hi[j] = f2bf_rne(f[j]);
      lo[j] = f2bf_rne(f[j] - bf2f(hi[j]));
    }
    long row = i >> kshift;
    int col = (int)(i & (K - 1));
    unsigned short* p0 = xcat + (row << (kshift + 1)) + col;
    *(ushort4*)p0 = make_ushort4(hi[0], hi[1], hi[2], hi[3]);
    *(ushort4*)(p0 + K) = make_ushort4(lo[0], lo[1], lo[2], lo[3]);
  }
}

// ---------- pass 2b: w -> ternary bf16, duplicated [N][2K] ----------
__global__ void prep_w_kernel(const float* __restrict__ w, unsigned short* __restrict__ wcat,
                              const double* __restrict__ sum, int kshift, long n,
                              double inv_cnt) {
  const int K = 1 << kshift;
  float scale = 1e-5f + (float)(*sum * inv_cnt);
  long stride = (long)gridDim.x * blockDim.x * 4;
  for (long i = ((long)blockIdx.x * blockDim.x + threadIdx.x) * 4; i < n; i += stride) {
    float4 v = *(const float4*)(w + i);
    float f[4] = {v.x, v.y, v.z, v.w};
    unsigned short q[4];
#pragma unroll
    for (int j = 0; j < 4; ++j) {
      float t = f[j] / scale;
      t = rintf(t);
      t = fminf(1.0f, fmaxf(-1.0f, t));
      q[j] = f2bf_rne(t);
    }
    long row = i >> kshift;
    int col = (int)(i & (K - 1));
    unsigned short* p0 = wcat + (row << (kshift + 1)) + col;
    *(ushort4*)p0 = make_ushort4(q[0], q[1], q[2], q[3]);
    *(ushort4*)(p0 + K) = make_ushort4(q[0], q[1], q[2], q[3]);
  }
}

// ---------- async global->LDS, 16B per lane ----------
__device__ __forceinline__ void gll16(const unsigned short* g, void* l) {
  __builtin_amdgcn_global_load_lds((const __attribute__((address_space(1))) unsigned int*)g,
                                   (__attribute__((address_space(3))) unsigned int*)l,
                                   16, 0, 0);
}

// =====================================================================
// 256x256 tile, BK=64 (128-B rows), dbuf=2, 8 waves, 4 phases/K-tile.
// m201 geometry: st_16x32 swizzle byte ^= ((byte>>9)&1)<<5  (flip bit5
// with row-bit-2). Linear gll16 dest + inverse-swizzled global source +
// swizzled ds_read (rule #21).
// LDS elems: A buf0 [0,16384) buf1 [16384,32768); B buf0 [32768,49152)
// buf1 [49152,65536). 128 KiB, 1 block/CU.
// Schedule per K-tile t (buf t&1): stage A(t+1)@P0, B(t+1)@P1 into
// buf (t+1)&1 (disjoint from read buf -> no WAR); vmcnt(0)@P3 (loads
// are 2-3 phases old ~600-900cyc -> drain ~free); RAW closed by
// vmcnt(0)+barrier before next iter's reads.
// Phases: P0 {8 rd: A m0-3 ks0 + B ks0, 16 MFMA} P1 {4 rd: A m4-7,
// 16 MFMA, b_ reused} P2/P3 same with ks1.
// =====================================================================
__global__ __launch_bounds__(512) void gemm4p_kernel(
    const unsigned short* __restrict__ A,
    const unsigned short* __restrict__ Bw,
    const float* __restrict__ bias,
    float* __restrict__ C, int M, int N) {
  constexpr int Kc = 4096;
  constexpr int NT = 64;                // Kc / 64
  __shared__ __align__(16) unsigned short lds[65536];  // 128 KiB

  const int nbx = N >> 8;
  const int nwg = (M >> 8) * nbx;
  // m204 bijective XCD swizzle
  const int q8 = nwg >> 3, r8 = nwg & 7;
  const int xcd = blockIdx.x & 7;
  const int loc = blockIdx.x >> 3;
  const int wgid = (xcd < r8 ? xcd * (q8 + 1) : r8 * (q8 + 1) + (xcd - r8) * q8) + loc;
  const int bx = wgid % nbx;
  const int by = wgid / nbx;
  const int bm = by << 8;
  const int bn = bx << 8;

  const int tid = threadIdx.x;
  const int lane = tid & 63;
  const int wid = tid >> 6;
  const int wr = wid >> 2;              // 0..1 : wave row (128 rows)
  const int wc = wid & 3;               // 0..3 : wave col (64 cols)

  f32x4 acc[8][4] = {};

  // ---- staging: thread stages rows (tid>>3)+64j, 16B at row-byte (tid&7)*16.
  // source col pre-swizzled: elem = ((tid&7)*8) ^ (((tid>>5)&1)*16)
  const int strow = tid >> 3;                                   // 0..63
  const int scole = ((tid & 7) * 8) ^ (((tid >> 5) & 1) * 16);  // elems
  const unsigned short* sA = A + (size_t)(bm + strow) * Kc + scole;
  const unsigned short* sB = Bw + (size_t)(bn + strow) * Kc + scole;
  const size_t rj = (size_t)64 * Kc;    // +64 rows source stride
  char* ldsb = (char*)lds;
  char* dbase = ldsb + (size_t)wid * 1024;  // + j*8192 + buf*32768 (+B:65536)

  // ---- frag read offsets (elems), st_16x32-swizzled ----
  // phys elem = row*64 + ((lane>>4)*8 ^ ((lane&4)*4)) + m*1024 + ks*32
  const int swz = ((lane >> 4) * 8) ^ ((lane & 4) * 4);
  const int aoff = wr * 8192 + (lane & 15) * 64 + swz;
  const int boff = 32768 + wc * 4096 + (lane & 15) * 64 + swz;

  // ---- prologue: stage tile 0 into buf 0 ----
#pragma unroll
  for (int j = 0; j < 4; ++j) {
    gll16(sA + j * rj, dbase + j * 8192);
    gll16(sB + j * rj, dbase + 65536 + j * 8192);
  }
  asm volatile("s_waitcnt vmcnt(0)" ::: "memory");
  __builtin_amdgcn_s_barrier();

  bf16x8 a_[4], b_[4];
  for (int t = 0; t < NT; ++t) {
    const int ab = aoff + (t & 1) * 16384;       // A base this tile
    const int bb = boff + (t & 1) * 16384;       // B base this tile
    const int sbuf = ((t + 1) & 1) * 32768;      // stage dest byte offset
    const int sk = (t + 1) * 64;                 // stage source k
    const bool doStage = (t + 1) < NT;

    // ---------------- P0: m0-3 x n0-3, ks0 ----------------
#pragma unroll
    for (int mi = 0; mi < 4; ++mi) a_[mi] = *(const bf16x8*)&lds[ab + mi * 1024];
#pragma unroll
    for (int ni = 0; ni < 4; ++ni) b_[ni] = *(const bf16x8*)&lds[bb + ni * 1024];
    if (doStage) {
#pragma unroll
      for (int j = 0; j < 4; ++j) gll16(sA + sk + j * rj, dbase + sbuf + j * 8192);
    }
    __builtin_amdgcn_s_barrier();
    asm volatile("s_waitcnt lgkmcnt(0)" ::: "memory");
    __builtin_amdgcn_sched_barrier(0);
    __builtin_amdgcn_s_setprio(1);
#pragma unroll
    for (int mi = 0; mi < 4; ++mi)
#pragma unroll
      for (int ni = 0; ni < 4; ++ni)
        acc[mi][ni] = __builtin_amdgcn_mfma_f32_16x16x32_bf16(a_[mi], b_[ni], acc[mi][ni], 0, 0, 0);
    __builtin_amdgcn_s_setprio(0);
    __builtin_amdgcn_s_barrier();

    // ---------------- P1: m4-7 x n0-3, ks0 (b_ reused) ----------------
#pragma unroll
    for (int mi = 0; mi < 4; ++mi) a_[mi] = *(const bf16x8*)&lds[ab + (mi + 4) * 1024];
    if (doStage) {
#pragma unroll
      for (int j = 0; j < 4; ++j) gll16(sB + sk + j * rj, dbase + sbuf + 65536 + j * 8192);
    }
    __builtin_amdgcn_s_barrier();
    asm volatile("s_waitcnt lgkmcnt(0)" ::: "memory");
    __builtin_amdgcn_sched_barrier(0);
    __builtin_amdgcn_s_setprio(1);
#pragma unroll
    for (int mi = 0; mi < 4; ++mi)
#pragma unroll
      for (int ni = 0; ni < 4; ++ni)
        acc[mi + 4][ni] = __builtin_amdgcn_mfma_f32_16x16x32_bf16(a_[mi], b_[ni], acc[mi + 4][ni], 0, 0, 0);
    __builtin_amdgcn_s_setprio(0);
    __builtin_amdgcn_s_barrier();

    // ---------------- P2: m0-3 x n0-3, ks1 ----------------
#pragma unroll
    for (int mi = 0; mi < 4; ++mi) a_[mi] = *(const bf16x8*)&lds[ab + mi * 1024 + 32];
#pragma unroll
    for (int ni = 0; ni < 4; ++ni) b_[ni] = *(const bf16x8*)&lds[bb + ni * 1024 + 32];
    __builtin_amdgcn_s_barrier();
    asm volatile("s_waitcnt lgkmcnt(0)" ::: "memory");
    __builtin_amdgcn_sched_barrier(0);
    __builtin_amdgcn_s_setprio(1);
#pragma unroll
    for (int mi = 0; mi < 4; ++mi)
#pragma unroll
      for (int ni = 0; ni < 4; ++ni)
        acc[mi][ni] = __builtin_amdgcn_mfma_f32_16x16x32_bf16(a_[mi], b_[ni], acc[mi][ni], 0, 0, 0);
    __builtin_amdgcn_s_setprio(0);
    __builtin_amdgcn_s_barrier();

    // ---------------- P3: m4-7 x n0-3, ks1 ----------------
#pragma unroll
    for (int mi = 0; mi < 4; ++mi) a_[mi] = *(const bf16x8*)&lds[ab + (mi + 4) * 1024 + 32];
    // tile t+1's loads issued at P0/P1 (2-3 phases ago) -> near-free drain
    asm volatile("s_waitcnt vmcnt(0)" ::: "memory");
    __builtin_amdgcn_s_barrier();
    asm volatile("s_waitcnt lgkmcnt(0)" ::: "memory");
    __builtin_amdgcn_sched_barrier(0);
    __builtin_amdgcn_s_setprio(1);
#pragma unroll
    for (int mi = 0; mi < 4; ++mi)
#pragma unroll
      for (int ni = 0; ni < 4; ++ni)
        acc[mi + 4][ni] = __builtin_amdgcn_mfma_f32_16x16x32_bf16(a_[mi], b_[ni], acc[mi + 4][ni], 0, 0, 0);
    __builtin_amdgcn_s_setprio(0);
    __builtin_amdgcn_s_barrier();
  }

  // ---- epilogue: C/D layout col=lane&15, row=(lane>>4)*4+reg ----
  const int r0 = bm + wr * 128 + (lane >> 4) * 4;
  const int c0 = bn + wc * 64 + (lane & 15);
#pragma unroll
  for (int ni = 0; ni < 4; ++ni) {
    const int col = c0 + ni * 16;
    const float bv = bias[col];
#pragma unroll
    for (int mi = 0; mi < 8; ++mi) {
#pragma unroll
      for (int rr = 0; rr < 4; ++rr)
        C[(size_t)(r0 + mi * 16 + rr) * N + col] = acc[mi][ni][rr] + bv;
    }
  }
}

// ---------- fallback (generic shapes / tiny ws): fp32 tiled ----------
__global__ void fallback_kernel(const float* __restrict__ x, const float* __restrict__ w,
                                const float* __restrict__ bias, const double* __restrict__ sum,
                                float* __restrict__ out, int M, int N, int K, double inv_cnt) {
  float scale = 1e-5f + (float)(*sum * inv_cnt);
  __shared__ float xs[64][33];
  __shared__ float qs[64][33];
  const int tid = threadIdx.x;
  const int bm = blockIdx.y * 64, bn = blockIdx.x * 64;
  const int ty = tid >> 4, tx = tid & 15;
  float acc[4][4] = {};
  for (int k0 = 0; k0 < K; k0 += 32) {
    for (int p = 0; p < 8; ++p) {
      int idx = p * 256 + tid;
      int r = idx >> 5, c = idx & 31;
      xs[r][c] = x[(size_t)(bm + r) * K + k0 + c];
      float t = w[(size_t)(bn + r) * K + k0 + c] / scale;
      t = rintf(t);
      qs[r][c] = fminf(1.0f, fmaxf(-1.0f, t));
    }
    __syncthreads();
    for (int kk = 0; kk < 32; ++kk) {
      float a[4], b[4];
#pragma unroll
      for (int i = 0; i < 4; ++i) a[i] = xs[ty * 4 + i][kk];
#pragma unroll
      for (int j = 0; j < 4; ++j) b[j] = qs[tx * 4 + j][kk];
#pragma unroll
      for (int i = 0; i < 4; ++i)
#pragma unroll
        for (int j = 0; j < 4; ++j) acc[i][j] += a[i] * b[j];
    }
    __syncthreads();
  }
#pragma unroll
  for (int i = 0; i < 4; ++i)
#pragma unroll
    for (int j = 0; j < 4; ++j)
      out[(size_t)(bm + ty * 4 + i) * N + bn + tx * 4 + j] = acc[i][j] + bias[bn + tx * 4 + j];
}

extern "C" void kernel_launch(void* const* d_in, const int* in_sizes, int n_in,
                              void* d_out, int out_size, void* d_ws, size_t ws_size,
                              hipStream_t stream) {
  const float* x = (const float*)d_in[0];
  const float* w = (const float*)d_in[1];
  const float* bias = (const float*)d_in[2];
  float* out = (float*)d_out;

  const int K = 2048;
  const int kshift = 11;          // log2(K)
  const int M = in_sizes[0] / K;  // 8192
  const int N = in_sizes[2];      // 8192
  const int Kc = 2 * K;           // 4096 (hi|lo)
  const long nw = (long)N * K;
  const long nx = (long)M * K;
  const double inv_cnt = 1.0 / (double)nw;

  double* sum = (double*)d_ws;
  hipMemsetAsync(d_ws, 0, sizeof(double), stream);
  absmean_kernel<<<2048, 256, 0, stream>>>(w, nw, sum);

  size_t need = 256 + ((size_t)M + (size_t)N) * (size_t)Kc * sizeof(unsigned short);
  bool shapes_ok = (K == 2048) && ((M & 255) == 0) && ((N & 255) == 0);
  if (shapes_ok && ws_size >= need) {
    unsigned short* xcat = (unsigned short*)((char*)d_ws + 256);
    unsigned short* wcat = xcat + (size_t)M * Kc;
    prep_x_kernel<<<2048, 256, 0, stream>>>(x, xcat, kshift, nx);
    prep_w_kernel<<<2048, 256, 0, stream>>>(w, wcat, sum, kshift, nw, inv_cnt);
    int nwg = (M >> 8) * (N >> 8);
    gemm4p_kernel<<<nwg, 512, 0, stream>>>(xcat, wcat, bias, out, M, N);
  } else {
    dim3 grid(N / 64, M / 64);
    fallback_kernel<<<grid, 256, 0, stream>>>(x, w, bias, sum, out, M, N, K, inv_cnt);
  }
}